// Round 1
// baseline (663.517 us; speedup 1.0000x reference)
//
#include <hip/hip_runtime.h>
#include <math.h>

#define NB   8
#define NPTS 4096
#define NTH  1024
#define SPT  4            // slots (elements) per thread
#define A_BIT 0x1000      // active flag
#define S_BIT 0x2000      // "has active suppressor" flag (this round)
#define N_BIT 0x4000      // next-round active flag

__device__ __forceinline__ int blockReduceSumI(int v, int* scr, int tid) {
    #pragma unroll
    for (int o = 32; o > 0; o >>= 1) v += __shfl_down(v, o, 64);
    if ((tid & 63) == 0) scr[tid >> 6] = v;
    __syncthreads();
    if (tid == 0) {
        int s = 0;
        #pragma unroll
        for (int w = 0; w < NTH / 64; ++w) s += scr[w];
        scr[16] = s;
    }
    __syncthreads();
    return scr[16];
}

__device__ __forceinline__ float blockReduceSumF(float v, float* scr, int tid) {
    #pragma unroll
    for (int o = 32; o > 0; o >>= 1) v += __shfl_down(v, o, 64);
    if ((tid & 63) == 0) scr[tid >> 6] = v;
    __syncthreads();
    if (tid == 0) {
        float s = 0.0f;
        #pragma unroll
        for (int w = 0; w < NTH / 64; ++w) s += scr[w];
        scr[16] = s;
    }
    __syncthreads();
    return scr[16];
}

__device__ __forceinline__ float rowAngleDeg(float a0, float a1, float a2,
                                             float b0, float b1, float b2) {
    float dot = a0 * b0 + a1 * b1 + a2 * b2;
    float na = sqrtf(a0 * a0 + a1 * a1 + a2 * a2);
    float nb = sqrtf(b0 * b0 + b1 * b1 + b2 * b2);
    float c = dot / (na * nb);
    c = fminf(1.0f, fmaxf(-1.0f, c));
    return acosf(c) * 57.29577951308232f;  // /pi*180
}

// One block per batch. LDS layout (57600 B static):
//   [0,32K)   u64 sort keys            (sort phase only)
//   [0,48K)   px/py/pz float[4096]x3   (after sort; overlays sort region)
//   [48K,56K) u16 fl[4096]: bits0-11 orig pred idx, bit12 a, bit13 s, bit14 a_new
//   [56K,..)  reduction scratch
__global__ __launch_bounds__(NTH) void molan_kernel(const float* __restrict__ pred,
                                                    const float* __restrict__ targ,
                                                    float* __restrict__ out) {
    __shared__ __align__(16) unsigned char lds[57600];
    unsigned long long* arr = (unsigned long long*)lds;
    float* px = (float*)lds;
    float* py = (float*)(lds + 16384);
    float* pz = (float*)(lds + 32768);
    unsigned short* fl = (unsigned short*)(lds + 49152);
    int*   scr_i = (int*)(lds + 57344);
    float* scr_f = (float*)(lds + 57344 + 128);

    const int b = blockIdx.x;
    const int tid = threadIdx.x;
    const float* pb = pred + (size_t)b * NPTS * 10;
    const float* tb = targ + (size_t)b * NPTS * 10;

    // ---- build sort keys: (conf desc, idx asc) as ascending u64 ----
    for (int s = 0; s < SPT; ++s) {
        int n = tid + s * NTH;
        float raw = pb[n * 10];
        float conf = 1.0f / (1.0f + expf(-raw));       // jax.nn.sigmoid
        float skey = (conf > 0.5f) ? conf : -INFINITY; // inactive -> -inf
        unsigned int u = __float_as_uint(skey);
        u = (u & 0x80000000u) ? ~u : (u | 0x80000000u); // float -> ascending uint
        u = ~u;                                          // -> descending
        arr[n] = ((unsigned long long)u << 32) | (unsigned int)n;
    }
    __syncthreads();

    // ---- bitonic sort, ascending on packed u64 ----
    for (int k = 2; k <= NPTS; k <<= 1) {
        for (int j = k >> 1; j > 0; j >>= 1) {
            for (int s = 0; s < SPT; ++s) {
                int i = tid + s * NTH;
                int p = i ^ j;
                if (p > i) {
                    unsigned long long a = arr[i], c = arr[p];
                    bool up = ((i & k) == 0);
                    if ((a > c) == up) { arr[i] = c; arr[p] = a; }
                }
            }
            __syncthreads();
        }
    }

    // ---- unpack own slots to registers, then overlay pos/flag arrays ----
    int   u_idx[SPT];
    bool  u_act[SPT];
    float u_px[SPT], u_py[SPT], u_pz[SPT];
    for (int s = 0; s < SPT; ++s) {
        int jslot = tid + s * NTH;
        unsigned long long e = arr[jslot];
        int n = (int)(e & 0xFFFFFFFFull);
        u_idx[s] = n;
        u_act[s] = ((unsigned int)(e >> 32)) != 0xFF800000u; // key != desc(-inf)
        float gz = (float)(n >> 10);
        float gx = (float)((n >> 5) & 31);
        float gy = (float)(n & 31);
        u_px[s] = (pb[n * 10 + 1] + gz) * 0.25f;    // /Z=4  (exact pow2)
        u_py[s] = (pb[n * 10 + 2] + gx) * 0.03125f; // /X=32
        u_pz[s] = (pb[n * 10 + 3] + gy) * 0.03125f; // /Y=32
    }
    __syncthreads();  // all reads of arr[] done before overwriting with px/py
    for (int s = 0; s < SPT; ++s) {
        int jslot = tid + s * NTH;
        px[jslot] = u_px[s];
        py[jslot] = u_py[s];
        pz[jslot] = u_pz[s];
        fl[jslot] = (unsigned short)(u_idx[s] | (u_act[s] ? A_BIT : 0));
    }
    __syncthreads();

    // ---- iterative NMS: exact reference fixpoint ----
    // reference loop runs >=1 step (prev init -1) and stops when active count
    // is unchanged; a_new is monotone-decreasing so equal count == fixpoint.
    int loc = 0;
    for (int s = 0; s < SPT; ++s) loc += (fl[tid + s * NTH] & A_BIT) ? 1 : 0;
    int cur = blockReduceSumI(loc, scr_i, tid);
    int prev = -1;
    while (cur != prev) {
        // pass 1: s[j] = exists active i<j with d<CUTOFF (early-exit scan)
        for (int s = 0; s < SPT; ++s) {
            int j = tid + s * NTH;
            unsigned short f = fl[j];
            unsigned short nf = (unsigned short)(f & ~S_BIT);
            if (f & A_BIT) {
                float xj = px[j], yj = py[j], zj = pz[j];
                for (int i = 0; i < j; ++i) {
                    if (fl[i] & A_BIT) {
                        float dx = px[i] - xj, dy = py[i] - yj, dz = pz[i] - zj;
                        if (dx * dx + dy * dy + dz * dz < 4.0f) { nf |= S_BIT; break; }
                    }
                }
            }
            fl[j] = nf;
        }
        __syncthreads();
        // pass 2: a_new[j] = a[j] && !(exists active i<j, !s[i], d<CUTOFF)
        for (int s = 0; s < SPT; ++s) {
            int j = tid + s * NTH;
            unsigned short f = fl[j];
            unsigned short nf = (unsigned short)(f & ~N_BIT);
            if (f & A_BIT) {
                bool suppressed = false;
                float xj = px[j], yj = py[j], zj = pz[j];
                for (int i = 0; i < j; ++i) {
                    unsigned short fi = fl[i];
                    if ((fi & A_BIT) && !(fi & S_BIT)) {
                        float dx = px[i] - xj, dy = py[i] - yj, dz = pz[i] - zj;
                        if (dx * dx + dy * dy + dz * dz < 4.0f) { suppressed = true; break; }
                    }
                }
                if (!suppressed) nf |= N_BIT;
            }
            fl[j] = nf;
        }
        __syncthreads();
        // commit a_new -> a, count
        loc = 0;
        for (int s = 0; s < SPT; ++s) {
            int j = tid + s * NTH;
            unsigned short f = fl[j];
            bool na = (f & N_BIT) != 0;
            fl[j] = (unsigned short)((f & ~(A_BIT | N_BIT)) | (na ? A_BIT : 0));
            loc += na ? 1 : 0;
        }
        prev = cur;
        cur = blockReduceSumI(loc, scr_i, tid);  // barriers inside
    }

    // ---- matching in real coords + stats ----
    int loc_ntg = 0;
    for (int s = 0; s < SPT; ++s) {
        int n = tid + s * NTH;
        if (tb[n * 10] > 0.5f) ++loc_ntg;
    }
    int loc_npd = 0, loc_tp = 0;
    float loc_ang = 0.0f;
    for (int s = 0; s < SPT; ++s) {
        int j = tid + s * NTH;
        unsigned short f = fl[j];
        if (!(f & A_BIT)) continue;
        ++loc_npd;
        float prx = px[j] * 25.0f, pry = py[j] * 25.0f, prz = pz[j] * 4.0f;
        int match = -1;
        for (int n = 0; n < NPTS; ++n) {  // first (lowest-index) matching target
            float tc = tb[n * 10];
            if (tc > 0.5f) {
                float gz = (float)(n >> 10);
                float gx = (float)((n >> 5) & 31);
                float gy = (float)(n & 31);
                float trx = (tb[n * 10 + 1] + gz) * 0.25f * 25.0f;
                float trg = (tb[n * 10 + 2] + gx) * 0.03125f * 25.0f;
                float trz = (tb[n * 10 + 3] + gy) * 0.03125f * 4.0f;
                float dx = trx - prx, dy = trg - pry, dz = trz - prz;
                if (dx * dx + dy * dy + dz * dz < 4.0f) { match = n; break; }
            }
        }
        if (match >= 0) {
            ++loc_tp;
            const float* pr = pb + (size_t)(f & 0x0FFF) * 10;  // original pred idx
            float ax0 = pr[4], ax1 = pr[5], ax2 = pr[6];
            float ay0 = pr[7], ay1 = pr[8], ay2 = pr[9];
            float az0 = ax1 * ay2 - ax2 * ay1;
            float az1 = ax2 * ay0 - ax0 * ay2;
            float az2 = ax0 * ay1 - ax1 * ay0;
            const float* tr = tb + (size_t)match * 10;
            float bx0 = tr[4], bx1 = tr[5], bx2 = tr[6];
            float by0 = tr[7], by1 = tr[8], by2 = tr[9];
            float bz0 = bx1 * by2 - bx2 * by1;
            float bz1 = bx2 * by0 - bx0 * by2;
            float bz2 = bx0 * by1 - bx1 * by0;
            loc_ang += rowAngleDeg(ax0, ax1, ax2, bx0, bx1, bx2);
            loc_ang += rowAngleDeg(ay0, ay1, ay2, by0, by1, by2);
            loc_ang += rowAngleDeg(az0, az1, az2, bz0, bz1, bz2);
        }
    }
    int n_tg = blockReduceSumI(loc_ntg, scr_i, tid);
    int n_pd = blockReduceSumI(loc_npd, scr_i, tid);
    int tp   = blockReduceSumI(loc_tp,  scr_i, tid);
    float angsum = blockReduceSumF(loc_ang, scr_f, tid);

    if (tid == 0) {
        out[b * 3 + 0] = (float)tp;
        out[b * 3 + 1] = (float)(n_pd - tp);
        out[b * 3 + 2] = (float)(n_tg - tp);
        out[NB * 3 + b] = (tp > 0) ? (angsum / (3.0f * (float)tp)) : 0.0f;
    }
}

extern "C" void kernel_launch(void* const* d_in, const int* in_sizes, int n_in,
                              void* d_out, int out_size, void* d_ws, size_t ws_size,
                              hipStream_t stream) {
    const float* pred = (const float*)d_in[0];
    const float* targ = (const float*)d_in[1];
    float* out = (float*)d_out;
    molan_kernel<<<dim3(NB), dim3(NTH), 0, stream>>>(pred, targ, out);
}

// Round 2
// 110.645 us; speedup vs baseline: 5.9968x; 5.9968x over previous
//
#include <hip/hip_runtime.h>
#include <math.h>

#define NB   8
#define NPTS 4096
#define NTH  1024
#define SPT  4            // slots (elements) per thread
#define A_BIT 0x1000      // active flag
#define S_BIT 0x2000      // "has active suppressor" flag (this round)
#define N_BIT 0x4000      // next-round active flag
#define KMAX 256          // kept-pred window size (slots per matching window)

__device__ __forceinline__ int blockReduceSumI(int v, int* scr, int tid) {
    #pragma unroll
    for (int o = 32; o > 0; o >>= 1) v += __shfl_down(v, o, 64);
    if ((tid & 63) == 0) scr[tid >> 6] = v;
    __syncthreads();
    if (tid == 0) {
        int s = 0;
        #pragma unroll
        for (int w = 0; w < NTH / 64; ++w) s += scr[w];
        scr[16] = s;
    }
    __syncthreads();
    return scr[16];
}

__device__ __forceinline__ float blockReduceSumF(float v, float* scr, int tid) {
    #pragma unroll
    for (int o = 32; o > 0; o >>= 1) v += __shfl_down(v, o, 64);
    if ((tid & 63) == 0) scr[tid >> 6] = v;
    __syncthreads();
    if (tid == 0) {
        float s = 0.0f;
        #pragma unroll
        for (int w = 0; w < NTH / 64; ++w) s += scr[w];
        scr[16] = s;
    }
    __syncthreads();
    return scr[16];
}

__device__ __forceinline__ float rowAngleDeg(float a0, float a1, float a2,
                                             float b0, float b1, float b2) {
    float dot = a0 * b0 + a1 * b1 + a2 * b2;
    float na = sqrtf(a0 * a0 + a1 * a1 + a2 * a2);
    float nb = sqrtf(b0 * b0 + b1 * b1 + b2 * b2);
    float c = dot / (na * nb);
    c = fminf(1.0f, fmaxf(-1.0f, c));
    return acosf(c) * 57.29577951308232f;  // /pi*180
}

// One block per batch. LDS layout (62336 B static):
//   [0,32K)        u64 sort keys       (sort phase only)
//   [0,48K)        px/py/pz f[4096]x3  (after sort; overlays sort region)
//   [48K,56K)      u16 fl[4096]: bits0-11 orig idx, bit12 a, bit13 s, bit14 a_new
//   57344..57472   int reduce scratch
//   57472..57600   float reduce scratch
//   57600..57664   wcount[16]   (kept preds per 256-slot window)
//   57664..57728   kcount
//   57728..62336   kp_x/y/z f[256], kp_slot u16[256], kp_match u32[256]
__global__ __launch_bounds__(NTH) void molan_kernel(const float* __restrict__ pred,
                                                    const float* __restrict__ targ,
                                                    float* __restrict__ out) {
    __shared__ __align__(16) unsigned char lds[62336];
    unsigned long long* arr = (unsigned long long*)lds;
    float* px = (float*)lds;
    float* py = (float*)(lds + 16384);
    float* pz = (float*)(lds + 32768);
    unsigned short* fl = (unsigned short*)(lds + 49152);
    int*   scr_i = (int*)(lds + 57344);
    float* scr_f = (float*)(lds + 57472);
    int*   wcount = (int*)(lds + 57600);
    int*   kcount = (int*)(lds + 57664);
    float* kp_x = (float*)(lds + 57728);
    float* kp_y = (float*)(lds + 58752);
    float* kp_z = (float*)(lds + 59776);
    unsigned short* kp_slot = (unsigned short*)(lds + 60800);
    unsigned int*   kp_match = (unsigned int*)(lds + 61312);

    const int b = blockIdx.x;
    const int tid = threadIdx.x;
    const float* pb = pred + (size_t)b * NPTS * 10;
    const float* tb = targ + (size_t)b * NPTS * 10;

    // ---- build sort keys: (conf desc, idx asc) as ascending u64 ----
    for (int s = 0; s < SPT; ++s) {
        int n = tid + s * NTH;
        float raw = pb[n * 10];
        float conf = 1.0f / (1.0f + expf(-raw));       // jax.nn.sigmoid
        float skey = (conf > 0.5f) ? conf : -INFINITY; // inactive -> -inf
        unsigned int u = __float_as_uint(skey);
        u = (u & 0x80000000u) ? ~u : (u | 0x80000000u); // float -> ascending uint
        u = ~u;                                          // -> descending
        arr[n] = ((unsigned long long)u << 32) | (unsigned int)n;
    }
    if (tid < 16) wcount[tid] = 0;
    __syncthreads();

    // ---- bitonic sort, ascending on packed u64 ----
    for (int k = 2; k <= NPTS; k <<= 1) {
        for (int j = k >> 1; j > 0; j >>= 1) {
            for (int s = 0; s < SPT; ++s) {
                int i = tid + s * NTH;
                int p = i ^ j;
                if (p > i) {
                    unsigned long long a = arr[i], c = arr[p];
                    bool up = ((i & k) == 0);
                    if ((a > c) == up) { arr[i] = c; arr[p] = a; }
                }
            }
            __syncthreads();
        }
    }

    // ---- unpack own slots to registers, then overlay pos/flag arrays ----
    int   u_idx[SPT];
    bool  u_act[SPT];
    float u_px[SPT], u_py[SPT], u_pz[SPT];
    for (int s = 0; s < SPT; ++s) {
        int jslot = tid + s * NTH;
        unsigned long long e = arr[jslot];
        int n = (int)(e & 0xFFFFFFFFull);
        u_idx[s] = n;
        u_act[s] = ((unsigned int)(e >> 32)) != 0xFF800000u; // key != desc(-inf)
        float gz = (float)(n >> 10);
        float gx = (float)((n >> 5) & 31);
        float gy = (float)(n & 31);
        u_px[s] = (pb[n * 10 + 1] + gz) * 0.25f;    // /Z=4  (exact pow2)
        u_py[s] = (pb[n * 10 + 2] + gx) * 0.03125f; // /X=32
        u_pz[s] = (pb[n * 10 + 3] + gy) * 0.03125f; // /Y=32
    }
    __syncthreads();  // all reads of arr[] done before overwriting with px/py
    for (int s = 0; s < SPT; ++s) {
        int jslot = tid + s * NTH;
        px[jslot] = u_px[s];
        py[jslot] = u_py[s];
        pz[jslot] = u_pz[s];
        fl[jslot] = (unsigned short)(u_idx[s] | (u_act[s] ? A_BIT : 0));
    }
    __syncthreads();

    // ---- iterative NMS: exact reference fixpoint ----
    int loc = 0;
    for (int s = 0; s < SPT; ++s) loc += (fl[tid + s * NTH] & A_BIT) ? 1 : 0;
    int cur = blockReduceSumI(loc, scr_i, tid);
    int prev = -1;
    while (cur != prev) {
        // pass 1: s[j] = exists active i<j with d<CUTOFF (early-exit scan)
        for (int s = 0; s < SPT; ++s) {
            int j = tid + s * NTH;
            unsigned short f = fl[j];
            unsigned short nf = (unsigned short)(f & ~S_BIT);
            if (f & A_BIT) {
                float xj = px[j], yj = py[j], zj = pz[j];
                for (int i = 0; i < j; ++i) {
                    if (fl[i] & A_BIT) {
                        float dx = px[i] - xj, dy = py[i] - yj, dz = pz[i] - zj;
                        if (dx * dx + dy * dy + dz * dz < 4.0f) { nf |= S_BIT; break; }
                    }
                }
            }
            fl[j] = nf;
        }
        __syncthreads();
        // pass 2: a_new[j] = a[j] && !(exists active i<j, !s[i], d<CUTOFF)
        for (int s = 0; s < SPT; ++s) {
            int j = tid + s * NTH;
            unsigned short f = fl[j];
            unsigned short nf = (unsigned short)(f & ~N_BIT);
            if (f & A_BIT) {
                bool suppressed = false;
                float xj = px[j], yj = py[j], zj = pz[j];
                for (int i = 0; i < j; ++i) {
                    unsigned short fi = fl[i];
                    if ((fi & A_BIT) && !(fi & S_BIT)) {
                        float dx = px[i] - xj, dy = py[i] - yj, dz = pz[i] - zj;
                        if (dx * dx + dy * dy + dz * dz < 4.0f) { suppressed = true; break; }
                    }
                }
                if (!suppressed) nf |= N_BIT;
            }
            fl[j] = nf;
        }
        __syncthreads();
        // commit a_new -> a, count
        loc = 0;
        for (int s = 0; s < SPT; ++s) {
            int j = tid + s * NTH;
            unsigned short f = fl[j];
            bool na = (f & N_BIT) != 0;
            fl[j] = (unsigned short)((f & ~(A_BIT | N_BIT)) | (na ? A_BIT : 0));
            loc += na ? 1 : 0;
        }
        prev = cur;
        cur = blockReduceSumI(loc, scr_i, tid);  // barriers inside
    }
    // cur == n_pd (final keep count)

    // ---- precompute this thread's targets (real coords) in registers ----
    bool  t_act[SPT];
    float t_x[SPT], t_y[SPT], t_z[SPT];
    int loc_ntg = 0;
    for (int s = 0; s < SPT; ++s) {
        int n = tid + s * NTH;
        float tc = tb[n * 10];
        bool a = tc > 0.5f;
        t_act[s] = a;
        if (a) ++loc_ntg;
        float gz = (float)(n >> 10);
        float gx = (float)((n >> 5) & 31);
        float gy = (float)(n & 31);
        t_x[s] = (tb[n * 10 + 1] + gz) * 0.25f * 25.0f;
        t_y[s] = (tb[n * 10 + 2] + gx) * 0.03125f * 25.0f;
        t_z[s] = (tb[n * 10 + 3] + gy) * 0.03125f * 4.0f;
    }

    // ---- count kept preds per 256-slot window ----
    for (int s = 0; s < SPT; ++s) {
        int j = tid + s * NTH;
        if (fl[j] & A_BIT) atomicAdd(&wcount[j >> 8], 1);
    }
    __syncthreads();

    // ---- matching: targets x kept-preds, first (lowest) target idx wins ----
    int loc_tp = 0;
    float loc_ang = 0.0f;
    for (int w = 0; w < NPTS / KMAX; ++w) {
        if (wcount[w] == 0) continue;  // uniform branch
        if (tid == 0) *kcount = 0;
        __syncthreads();
        // build kept-pred entries for this window (real coords)
        for (int s = 0; s < SPT; ++s) {
            int j = tid + s * NTH;
            if ((j >> 8) == w && (fl[j] & A_BIT)) {
                int e = atomicAdd(kcount, 1);
                kp_slot[e] = (unsigned short)j;
                kp_x[e] = px[j] * 25.0f;
                kp_y[e] = py[j] * 25.0f;
                kp_z[e] = pz[j] * 4.0f;
                kp_match[e] = 0xFFFFFFFFu;
            }
        }
        __syncthreads();
        const int K = wcount[w];
        // every active target tests against every kept pred in this window
        for (int s = 0; s < SPT; ++s) {
            if (!t_act[s]) continue;
            int n = tid + s * NTH;
            float tx = t_x[s], ty = t_y[s], tz = t_z[s];
            for (int e = 0; e < K; ++e) {
                float dx = tx - kp_x[e], dy = ty - kp_y[e], dz = tz - kp_z[e];
                if (dx * dx + dy * dy + dz * dz < 4.0f)
                    atomicMin(&kp_match[e], (unsigned int)n);
            }
        }
        __syncthreads();
        // finalize: one thread per entry computes the rotation-angle error
        if (tid < K) {
            unsigned int m = kp_match[tid];
            if (m != 0xFFFFFFFFu) {
                ++loc_tp;
                const float* pr = pb + (size_t)(fl[kp_slot[tid]] & 0x0FFF) * 10;
                float ax0 = pr[4], ax1 = pr[5], ax2 = pr[6];
                float ay0 = pr[7], ay1 = pr[8], ay2 = pr[9];
                float az0 = ax1 * ay2 - ax2 * ay1;
                float az1 = ax2 * ay0 - ax0 * ay2;
                float az2 = ax0 * ay1 - ax1 * ay0;
                const float* tr = tb + (size_t)m * 10;
                float bx0 = tr[4], bx1 = tr[5], bx2 = tr[6];
                float by0 = tr[7], by1 = tr[8], by2 = tr[9];
                float bz0 = bx1 * by2 - bx2 * by1;
                float bz1 = bx2 * by0 - bx0 * by2;
                float bz2 = bx0 * by1 - bx1 * by0;
                loc_ang += rowAngleDeg(ax0, ax1, ax2, bx0, bx1, bx2);
                loc_ang += rowAngleDeg(ay0, ay1, ay2, by0, by1, by2);
                loc_ang += rowAngleDeg(az0, az1, az2, bz0, bz1, bz2);
            }
        }
        __syncthreads();  // region reused by next nonempty window
    }

    int n_tg = blockReduceSumI(loc_ntg, scr_i, tid);
    int tp   = blockReduceSumI(loc_tp,  scr_i, tid);
    float angsum = blockReduceSumF(loc_ang, scr_f, tid);
    const int n_pd = cur;

    if (tid == 0) {
        out[b * 3 + 0] = (float)tp;
        out[b * 3 + 1] = (float)(n_pd - tp);
        out[b * 3 + 2] = (float)(n_tg - tp);
        out[NB * 3 + b] = (tp > 0) ? (angsum / (3.0f * (float)tp)) : 0.0f;
    }
}

extern "C" void kernel_launch(void* const* d_in, const int* in_sizes, int n_in,
                              void* d_out, int out_size, void* d_ws, size_t ws_size,
                              hipStream_t stream) {
    const float* pred = (const float*)d_in[0];
    const float* targ = (const float*)d_in[1];
    float* out = (float*)d_out;
    molan_kernel<<<dim3(NB), dim3(NTH), 0, stream>>>(pred, targ, out);
}

// Round 3
// 93.951 us; speedup vs baseline: 7.0624x; 1.1777x over previous
//
#include <hip/hip_runtime.h>
#include <math.h>

#define NB   8
#define NPTS 4096
#define NTH  1024
#define SPT  4            // consecutive elements per thread
#define CAP  64           // capped pass-1 scan length
#define MAXQ 256
#define MAXU 256
#define SENT 30000.0f

__device__ __forceinline__ int blockReduceSumI(int v, int* scr, int tid) {
    #pragma unroll
    for (int o = 32; o > 0; o >>= 1) v += __shfl_down(v, o, 64);
    if ((tid & 63) == 0) scr[tid >> 6] = v;
    __syncthreads();
    if (tid == 0) {
        int s = 0;
        #pragma unroll
        for (int w = 0; w < NTH / 64; ++w) s += scr[w];
        scr[16] = s;
    }
    __syncthreads();
    return scr[16];
}

__device__ __forceinline__ float blockReduceSumF(float v, float* scr, int tid) {
    #pragma unroll
    for (int o = 32; o > 0; o >>= 1) v += __shfl_down(v, o, 64);
    if ((tid & 63) == 0) scr[tid >> 6] = v;
    __syncthreads();
    if (tid == 0) {
        float s = 0.0f;
        #pragma unroll
        for (int w = 0; w < NTH / 64; ++w) s += scr[w];
        scr[16] = s;
    }
    __syncthreads();
    return scr[16];
}

__device__ __forceinline__ float rowAngleDeg(float a0, float a1, float a2,
                                             float b0, float b1, float b2) {
    float dot = a0 * b0 + a1 * b1 + a2 * b2;
    float na = sqrtf(a0 * a0 + a1 * a1 + a2 * a2);
    float nb = sqrtf(b0 * b0 + b1 * b1 + b2 * b2);
    float c = dot / (na * nb);
    c = fminf(1.0f, fmaxf(-1.0f, c));
    return acosf(c) * 57.29577951308232f;  // /pi*180
}

__device__ __forceinline__ void cmpswap(unsigned long long &a, unsigned long long &b, bool up) {
    // (lower=a, upper=b): swap if (a > b) == up
    if ((a > b) == up) { unsigned long long t = a; a = b; b = t; }
}

// One block per batch. LDS layout (59744 B):
//   [0,32K)        u64 arr[4096] (sort scratch) / float2 pxy[4096] (after sort)
//   32768..49152   float pz[4096]
//   49152..49280   int scr_i[32]
//   49280..49408   float scr_f[32]
//   49408..49424   int cnt[4]   (qn, un, kc)
//   49424..49488   int wcount[16]
//   49504..53600   qs_slot i32[256], qs_x/y/z f32[256]   (queue / U-list / kp)
//   53600..54624   sres i32[256]  (coop results / kp_match)
//   54624..55648   kp_idx i32[256]
//   55648..59744   sarr u8[4096]  (per-slot "unsuppressed active" for fallback)
__global__ __launch_bounds__(NTH) void molan_kernel(const float* __restrict__ pred,
                                                    const float* __restrict__ targ,
                                                    float* __restrict__ out) {
    __shared__ __align__(16) unsigned char lds[59744];
    unsigned long long* arr = (unsigned long long*)lds;
    float2* pxy = (float2*)lds;
    float*  pz  = (float*)(lds + 32768);
    int*    scr_i = (int*)(lds + 49152);
    float*  scr_f = (float*)(lds + 49280);
    int*    cnt   = (int*)(lds + 49408);
    int*    wcount = (int*)(lds + 49424);
    int*    qs_slot = (int*)(lds + 49504);
    float*  qs_x = (float*)(lds + 50528);
    float*  qs_y = (float*)(lds + 51552);
    float*  qs_z = (float*)(lds + 52576);
    int*    sres = (int*)(lds + 53600);
    unsigned int* kp_match = (unsigned int*)(lds + 53600);  // reuse after NMS
    int*    kp_idx = (int*)(lds + 54624);
    unsigned char* sarr = lds + 55648;

    const int b = blockIdx.x;
    const int tid = threadIdx.x;
    const int lane = tid & 63;
    const float* pb = pred + (size_t)b * NPTS * 10;
    const float* tb = targ + (size_t)b * NPTS * 10;

    // ---- build sort keys in registers: (conf desc, idx asc) ascending u64 ----
    unsigned long long r[SPT];
    #pragma unroll
    for (int s = 0; s < SPT; ++s) {
        int n = 4 * tid + s;
        float raw = pb[n * 10];
        float conf = 1.0f / (1.0f + expf(-raw));       // jax.nn.sigmoid
        float skey = (conf > 0.5f) ? conf : -INFINITY; // inactive -> -inf
        unsigned int u = __float_as_uint(skey);
        u = (u & 0x80000000u) ? ~u : (u | 0x80000000u); // float -> ascending uint
        u = ~u;                                          // -> descending
        r[s] = ((unsigned long long)u << 32) | (unsigned int)n;
    }

    // ---- hierarchical bitonic sort ----
    for (int k = 2; k <= NPTS; k <<= 1) {
        int j = k >> 1;
        if (j >= 256) {
            __syncthreads();  // protect prior LDS reads before overwriting
            #pragma unroll
            for (int s = 0; s < SPT; ++s) arr[4 * tid + s] = r[s];
            __syncthreads();
            for (; j >= 256; j >>= 1) {
                #pragma unroll
                for (int s = 0; s < SPT; ++s) {
                    int i = tid + s * NTH;
                    int p = i ^ j;
                    if (p > i) {
                        unsigned long long a = arr[i], c = arr[p];
                        bool up = ((i & k) == 0);
                        if ((a > c) == up) { arr[i] = c; arr[p] = a; }
                    }
                }
                __syncthreads();
            }
            #pragma unroll
            for (int s = 0; s < SPT; ++s) r[s] = arr[4 * tid + s];
        }
        for (; j >= 4; j >>= 1) {          // intra-wave via shuffles
            const int d = j >> 2;
            const bool lower = ((lane & d) == 0);
            const bool up = (((tid << 2) & k) == 0);
            #pragma unroll
            for (int s = 0; s < SPT; ++s) {
                unsigned long long mine = r[s];
                unsigned long long other = __shfl(mine, lane ^ d, 64);
                unsigned long long mn = mine < other ? mine : other;
                unsigned long long mx = mine < other ? other : mine;
                r[s] = (lower == up) ? mn : mx;
            }
        }
        if (k >= 4) {                      // j == 2, in-thread
            cmpswap(r[0], r[2], (((tid << 2) + 0) & k) == 0);
            cmpswap(r[1], r[3], (((tid << 2) + 1) & k) == 0);
        }
        cmpswap(r[0], r[1], (((tid << 2) + 0) & k) == 0);  // j == 1
        cmpswap(r[2], r[3], (((tid << 2) + 2) & k) == 0);
    }

    // ---- unpack sorted slots, gather positions ----
    int   rIdx[SPT];
    bool  rAct[SPT];
    float cx[SPT], cy[SPT], cz[SPT];
    #pragma unroll
    for (int s = 0; s < SPT; ++s) {
        int n = (int)(r[s] & 0xFFFFFFFFull);
        bool act = ((unsigned int)(r[s] >> 32)) != 0xFF800000u; // key != desc(-inf)
        rIdx[s] = n;
        rAct[s] = act;
        float gz = (float)(n >> 10);
        float gx = (float)((n >> 5) & 31);
        float gy = (float)(n & 31);
        float x = (pb[n * 10 + 1] + gz) * 0.25f;
        float y = (pb[n * 10 + 2] + gx) * 0.03125f;
        float z = (pb[n * 10 + 3] + gy) * 0.03125f;
        cx[s] = act ? x : SENT;
        cy[s] = act ? y : SENT;
        cz[s] = act ? z : SENT;
    }
    // targets in registers early (hide global latency under NMS)
    bool  t_act[SPT];
    float t_x[SPT], t_y[SPT], t_z[SPT];
    int loc_ntg = 0;
    #pragma unroll
    for (int s = 0; s < SPT; ++s) {
        int n = 4 * tid + s;
        bool a = tb[n * 10] > 0.5f;
        t_act[s] = a;
        if (a) ++loc_ntg;
        float gz = (float)(n >> 10);
        float gx = (float)((n >> 5) & 31);
        float gy = (float)(n & 31);
        t_x[s] = (tb[n * 10 + 1] + gz) * 0.25f * 25.0f;
        t_y[s] = (tb[n * 10 + 2] + gx) * 0.03125f * 25.0f;
        t_z[s] = (tb[n * 10 + 3] + gy) * 0.03125f * 4.0f;
    }
    __syncthreads();  // all arr reads complete before overlaying pxy
    #pragma unroll
    for (int s = 0; s < SPT; ++s) {
        int jslot = 4 * tid + s;
        pxy[jslot] = make_float2(cx[s], cy[s]);
        pz[jslot] = cz[s];
    }
    if (tid < 16) wcount[tid] = 0;
    __syncthreads();

    // ---- NMS fixpoint (exact reference semantics) ----
    int loc = 0;
    #pragma unroll
    for (int s = 0; s < SPT; ++s) loc += rAct[s] ? 1 : 0;
    int cur = blockReduceSumI(loc, scr_i, tid);
    int prev = -1;
    bool sS[SPT];
    while (cur != prev) {
        if (tid == 0) cnt[0] = 0;
        __syncthreads();
        // pass 1: capped early-exit scan; undecided -> queue
        int qe[SPT];
        #pragma unroll
        for (int s = 0; s < SPT; ++s) {
            qe[s] = -1;
            sS[s] = false;
            if (!rAct[s]) continue;
            int jslot = 4 * tid + s;
            float xj = cx[s], yj = cy[s], zj = cz[s];
            int L = min(jslot, CAP);
            bool found = false;
            for (int i = 0; i < L; ++i) {
                float2 q = pxy[i];
                float dx = q.x - xj, dy = q.y - yj, dz = pz[i] - zj;
                if (dx * dx + dy * dy + dz * dz < 4.0f) { found = true; break; }
            }
            if (found) { sS[s] = true; }
            else if (jslot > CAP) {
                int e = atomicAdd(&cnt[0], 1);
                if (e < MAXQ) {
                    qs_slot[e] = jslot; qs_x[e] = xj; qs_y[e] = yj; qs_z[e] = zj;
                    sres[e] = 0; qe[s] = e;
                } else {  // overflow fallback: full serial scan
                    for (int i = CAP; i < jslot; ++i) {
                        float2 q = pxy[i];
                        float dx = q.x - xj, dy = q.y - yj, dz = pz[i] - zj;
                        if (dx * dx + dy * dy + dz * dz < 4.0f) { sS[s] = true; break; }
                    }
                }
            }
        }
        __syncthreads();
        // cooperative resolve: all threads test their slots vs all queue entries
        int Q = min(cnt[0], MAXQ);
        if (Q > 0) {
            for (int e = 0; e < Q; ++e) {
                int qj = qs_slot[e];
                float qx = qs_x[e], qy = qs_y[e], qz = qs_z[e];
                int hit = 0;
                #pragma unroll
                for (int s = 0; s < SPT; ++s) {
                    int i = 4 * tid + s;
                    float dx = cx[s] - qx, dy = cy[s] - qy, dz = cz[s] - qz;
                    if (i < qj && dx * dx + dy * dy + dz * dz < 4.0f) hit = 1;
                }
                if (hit) atomicOr(&sres[e], 1);
            }
        }
        __syncthreads();
        #pragma unroll
        for (int s = 0; s < SPT; ++s)
            if (qe[s] >= 0) sS[s] = (sres[qe[s]] != 0);
        // record "unsuppressed active" bytes for overflow fallback
        {
            unsigned int pk = 0;
            #pragma unroll
            for (int s = 0; s < SPT; ++s)
                if (rAct[s] && !sS[s]) pk |= (1u << (8 * s));
            ((unsigned int*)sarr)[tid] = pk;
        }
        if (tid == 0) cnt[1] = 0;
        __syncthreads();  // also: queue-region reads done before U overwrites it
        // build compact U = {active && !s}
        #pragma unroll
        for (int s = 0; s < SPT; ++s) {
            if (rAct[s] && !sS[s]) {
                int e = atomicAdd(&cnt[1], 1);
                if (e < MAXU) {
                    qs_slot[e] = 4 * tid + s;
                    qs_x[e] = cx[s]; qs_y[e] = cy[s]; qs_z[e] = cz[s];
                }
            }
        }
        __syncthreads();
        // pass 2: suppressed iff exists u in U with slot<j within cutoff
        int Ku = cnt[1];
        loc = 0;
        #pragma unroll
        for (int s = 0; s < SPT; ++s) {
            if (!rAct[s]) continue;
            int jslot = 4 * tid + s;
            bool supp = false;
            if (Ku <= MAXU) {
                for (int e = 0; e < Ku; ++e) {
                    if (qs_slot[e] < jslot) {
                        float dx = qs_x[e] - cx[s], dy = qs_y[e] - cy[s], dz = qs_z[e] - cz[s];
                        if (dx * dx + dy * dy + dz * dz < 4.0f) { supp = true; break; }
                    }
                }
            } else {  // overflow fallback: scan all earlier slots via sarr
                for (int i = 0; i < jslot; ++i) {
                    if (sarr[i]) {
                        float2 q = pxy[i];
                        float dx = q.x - cx[s], dy = q.y - cy[s], dz = pz[i] - cz[s];
                        if (dx * dx + dy * dy + dz * dz < 4.0f) { supp = true; break; }
                    }
                }
            }
            if (supp) {
                rAct[s] = false;
                cx[s] = cy[s] = cz[s] = SENT;
                pxy[jslot] = make_float2(SENT, SENT);
                pz[jslot] = SENT;
            } else ++loc;
        }
        prev = cur;
        cur = blockReduceSumI(loc, scr_i, tid);  // barriers inside publish commits
    }
    const int n_pd = cur;

    // ---- matching: per-window kept preds vs all targets ----
    #pragma unroll
    for (int s = 0; s < SPT; ++s)
        if (rAct[s]) atomicAdd(&wcount[(4 * tid + s) >> 8], 1);
    __syncthreads();

    int loc_tp = 0;
    float loc_ang = 0.0f;
    for (int w = 0; w < 16; ++w) {
        if (wcount[w] == 0) continue;  // uniform branch
        if (tid == 0) cnt[2] = 0;
        __syncthreads();
        #pragma unroll
        for (int s = 0; s < SPT; ++s) {
            int jslot = 4 * tid + s;
            if ((jslot >> 8) == w && rAct[s]) {
                int e = atomicAdd(&cnt[2], 1);
                kp_idx[e] = rIdx[s];
                qs_x[e] = cx[s] * 25.0f;
                qs_y[e] = cy[s] * 25.0f;
                qs_z[e] = cz[s] * 4.0f;
                kp_match[e] = 0xFFFFFFFFu;
            }
        }
        __syncthreads();
        const int K = wcount[w];
        #pragma unroll
        for (int s = 0; s < SPT; ++s) {
            if (!t_act[s]) continue;
            int n = 4 * tid + s;
            float tx = t_x[s], ty = t_y[s], tz = t_z[s];
            for (int e = 0; e < K; ++e) {
                float dx = tx - qs_x[e], dy = ty - qs_y[e], dz = tz - qs_z[e];
                if (dx * dx + dy * dy + dz * dz < 4.0f)
                    atomicMin(&kp_match[e], (unsigned int)n);
            }
        }
        __syncthreads();
        if (tid < K) {
            unsigned int m = kp_match[tid];
            if (m != 0xFFFFFFFFu) {
                ++loc_tp;
                const float* pr = pb + (size_t)kp_idx[tid] * 10;
                float ax0 = pr[4], ax1 = pr[5], ax2 = pr[6];
                float ay0 = pr[7], ay1 = pr[8], ay2 = pr[9];
                float az0 = ax1 * ay2 - ax2 * ay1;
                float az1 = ax2 * ay0 - ax0 * ay2;
                float az2 = ax0 * ay1 - ax1 * ay0;
                const float* tr = tb + (size_t)m * 10;
                float bx0 = tr[4], bx1 = tr[5], bx2 = tr[6];
                float by0 = tr[7], by1 = tr[8], by2 = tr[9];
                float bz0 = bx1 * by2 - bx2 * by1;
                float bz1 = bx2 * by0 - bx0 * by2;
                float bz2 = bx0 * by1 - bx1 * by0;
                loc_ang += rowAngleDeg(ax0, ax1, ax2, bx0, bx1, bx2);
                loc_ang += rowAngleDeg(ay0, ay1, ay2, by0, by1, by2);
                loc_ang += rowAngleDeg(az0, az1, az2, bz0, bz1, bz2);
            }
        }
        __syncthreads();  // region reused by next nonempty window
    }

    int n_tg = blockReduceSumI(loc_ntg, scr_i, tid);
    int tp   = blockReduceSumI(loc_tp,  scr_i, tid);
    float angsum = blockReduceSumF(loc_ang, scr_f, tid);

    if (tid == 0) {
        out[b * 3 + 0] = (float)tp;
        out[b * 3 + 1] = (float)(n_pd - tp);
        out[b * 3 + 2] = (float)(n_tg - tp);
        out[NB * 3 + b] = (tp > 0) ? (angsum / (3.0f * (float)tp)) : 0.0f;
    }
}

extern "C" void kernel_launch(void* const* d_in, const int* in_sizes, int n_in,
                              void* d_out, int out_size, void* d_ws, size_t ws_size,
                              hipStream_t stream) {
    const float* pred = (const float*)d_in[0];
    const float* targ = (const float*)d_in[1];
    float* out = (float*)d_out;
    molan_kernel<<<dim3(NB), dim3(NTH), 0, stream>>>(pred, targ, out);
}